// Round 1
// baseline (2480.004 us; speedup 1.0000x reference)
//
#include <hip/hip_runtime.h>
#include <stdint.h>

#define GAS __attribute__((address_space(1)))
#define LAS __attribute__((address_space(3)))

typedef __bf16 v8bf __attribute__((ext_vector_type(8)));
typedef float v4f __attribute__((ext_vector_type(4)));
typedef unsigned short u16;
typedef unsigned long long u64;

constexpr int kB = 256, kT = 128, kI = 512, kH = 1024, kO = 32;
constexpr int kBlocks = 256, kThreads = 256;
constexpr int KSX = kI / 32;   // 16 k-slices of 32 in x
constexpr int KSH = kH / 32;   // 32 k-slices of 32 in h
constexpr int QX = KSX / 4;    // 4  x-slices per wave (k-split)
constexpr int QH = KSH / 4;    // 8  h-slices per wave

// workspace layout (bytes): FLG | XT | WIT[4] | WHT[4] | H-rotation (last,
// flexible length so a small workspace degrades to the 2-slot coherent path).
constexpr size_t OFF_FLG  = 0;
constexpr size_t OFF_XT   = 8192;
constexpr size_t SZ_XT    = (size_t)kB * kT * kI * 2;           // 32 MB
constexpr size_t OFF_WIT  = OFF_XT + SZ_XT;
constexpr size_t SZ_WIT   = (size_t)kH * kI * 2;                // 1 MB / gate
constexpr size_t OFF_WHT  = OFF_WIT + 4 * SZ_WIT;
constexpr size_t SZ_WHT   = (size_t)kH * kH * 2;                // 2 MB / gate
constexpr size_t OFF_H    = OFF_WHT + 4 * SZ_WHT;
constexpr size_t SZ_H1    = (size_t)kB * kH * 2;                // 512 KB / slot
constexpr size_t NEED_ROT = OFF_H + (size_t)(kT + 1) * SZ_H1;   // ~108.5 MB
constexpr size_t NEED_MIN = OFF_H + 2 * SZ_H1;                  // ~45 MB (proven)

struct LstmParams {
  const u16* xt;        // frag-tiled x: [t][mt][mi][ks(16)][lane][8]
  const u16* wit[4];    // frag-tiled wi: [ut][ks(16)][lane][8], gates i,f,g,o
  const u16* wht[4];    // frag-tiled wh: [ut][ks(32)][lane][8]
  const float* bi[4];
  const float* bh[4];
  const float* wfc;     // fp32 [O][H]
  float* out;           // fp32 [B][O]
  unsigned* flags;      // per-group 4 padded sub-counters (256B apart)
  u16* hbuf;            // rot x frag-layout h: [mt][mi][ks(32)][lane][8]
  int rot;              // 1: 129-slot rotation + cached L2-multicast h reads
                        // 0: legacy 2-slot sc0|sc1 LLC-coherent path
};

static __device__ __forceinline__ float b2f(u16 v) {
  union { float f; uint32_t i; } u; u.i = ((uint32_t)v) << 16; return u.f;
}
static __device__ __forceinline__ u16 f2b(float f) {
  union { float f; uint32_t i; } u; u.f = f;
  return (u16)((u.i + 0x7fffu + ((u.i >> 16) & 1u)) >> 16);
}
static __device__ __forceinline__ float sigm(float x) { return 1.f / (1.f + __expf(-x)); }
static __device__ __forceinline__ float tanh_f(float x) {
  float e = __expf(2.f * x);
  return 1.f - 2.f / (e + 1.f);
}
// coherent async global->LDS, 16B/lane, sc0|sc1 (bypass L1/L2, LLC-serviced).
// FALLBACK path only (r2-r4 proven). RULE (r7): a vmcnt(0) wait must sit
// between the issue and any ds_read of the destination.
static __device__ __forceinline__ void ld16c(const void* g, void* l) {
  __builtin_amdgcn_global_load_lds((const GAS uint32_t*)g, (LAS uint32_t*)l, 16, 0, 0x11);
}

// ---- prepass: fp32 -> bf16 frag-tiling -------------------------------------
// x[m][t][k] -> xt frag order [t][mt][mi][ks][lane][8]
__global__ __launch_bounds__(256) void cvt_x_tile(const float* __restrict__ x,
                                                  u16* __restrict__ xt) {
  const int gid = blockIdx.x * 256 + threadIdx.x;    // 2^21 threads exactly
  const int lane = gid & 63;
  const int ks = (gid >> 6) & 15;
  const int mi = (gid >> 10) & 3;
  const int mt = (gid >> 12) & 3;
  const int t  = gid >> 14;
  const int m = mt * 64 + mi * 16 + (lane & 15);
  const int k = ks * 32 + (lane >> 4) * 8;
  const float4* s = (const float4*)(x + ((size_t)m * kT + t) * kI + k);
  const float4 a = s[0], b = s[1];
  uint4 o = {f2b(a.x) | ((uint32_t)f2b(a.y) << 16), f2b(a.z) | ((uint32_t)f2b(a.w) << 16),
             f2b(b.x) | ((uint32_t)f2b(b.y) << 16), f2b(b.z) | ((uint32_t)f2b(b.w) << 16)};
  *(uint4*)(xt + (size_t)gid * 8) = o;
}

// W[u][k] (row-major, K=512 or 1024) -> frag order [ut][ks][lane][8]
__global__ __launch_bounds__(256) void cvt_w_tile(const float* __restrict__ w,
                                                  u16* __restrict__ wt,
                                                  int K, int lgKS) {
  const int gid = blockIdx.x * 256 + threadIdx.x;
  const int lane = gid & 63;
  const int rest = gid >> 6;
  const int ks = rest & ((1 << lgKS) - 1);
  const int ut2 = rest >> lgKS;
  const int u = ut2 * 16 + (lane & 15);
  const int k = ks * 32 + (lane >> 4) * 8;
  const float4* s = (const float4*)(w + (size_t)u * K + k);
  const float4 a = s[0], b = s[1];
  uint4 o = {f2b(a.x) | ((uint32_t)f2b(a.y) << 16), f2b(a.z) | ((uint32_t)f2b(a.w) << 16),
             f2b(b.x) | ((uint32_t)f2b(b.y) << 16), f2b(b.z) | ((uint32_t)f2b(b.w) << 16)};
  *(uint4*)(wt + (size_t)gid * 8) = o;
}

// ---- persistent recurrence kernel ------------------------------------------
__global__ __launch_bounds__(kThreads, 2) void lstm_kernel(LstmParams p) {
  // LDS map: [0,128K) per-wave h staging chunks (fallback path only); Red
  // (64 KB) overlaid on [0,64K). [128K,130K) Hout repack tile. shFC (16 KB)
  // overlaid at 0 post-loop.
  __shared__ __align__(16) char smem[133120];
  v4f* Red = (v4f*)smem;              // [slot = wvp*16+g*4+m][lane]
  u16* Hout = (u16*)(smem + 131072);  // [64 rows][16 units]
  u16* shFC = (u16*)smem;             // 8 rows x 1024 bf16 (post-loop only)

  const int tid = threadIdx.x;
  const int lane = tid & 63;
  const int wv = tid >> 6;           // wave = K-quarter owner AND m-tile owner in combine
  const int blk = blockIdx.x;
  const int mt = blk & 3;            // batch tile 0..3 = barrier group
  const int ut = blk >> 2;           // 0..63: 16 hidden units (x4 gates)

  const int mloc = lane & 15;
  const int q = lane >> 4;
  const int uglob = ut * 16 + mloc;

  // 4 padded sub-counters per group (256B apart): producer (mt,ut) bumps
  // sub (ut&3); each sub reaches 16*t when step t-1 is fully published.
  // vs the old 64-flag/16-line scheme this cuts LLC poll-line pressure 4x
  // (and s_sleep(4) cuts the poll rate another 4x).
  unsigned* gflags = p.flags + mt * 256;

  float bias[4];
#pragma unroll
  for (int g = 0; g < 4; ++g) bias[g] = p.bi[g][uglob] + p.bh[g][uglob];

  float creg[4] = {0.f, 0.f, 0.f, 0.f};    // cell state for rows mt*64+wv*16+q*4+r

  // ---- h-weights resident in registers (128 VGPRs); x-weights streamed ----
  v8bf bhh[QH][4];
#pragma unroll
  for (int g = 0; g < 4; ++g)
#pragma unroll
    for (int i = 0; i < QH; ++i)
      bhh[i][g] = *((const v8bf*)p.wht[g] + ((size_t)(ut * KSH + wv * QH + i) * 64 + lane));

  for (int t = 0; t < kT; ++t) {
    v4f acc[4][4];    // [m-tile][gate] partials for this wave's K-quarter
#pragma unroll
    for (int m = 0; m < 4; ++m)
#pragma unroll
      for (int g = 0; g < 4; ++g) acc[m][g] = (v4f){0.f, 0.f, 0.f, 0.f};

    // ---- phase X: x-part MFMAs, pre-poll (independent of h); wi from L2 ----
    const v8bf* xf = (const v8bf*)p.xt + ((size_t)(t * 4 + mt) * 4 * KSX) * 64;
#pragma unroll
    for (int i = 0; i < QX; ++i) {
      v8bf bxl[4];
#pragma unroll
      for (int g = 0; g < 4; ++g)
        bxl[g] = *((const v8bf*)p.wit[g] + ((size_t)(ut * KSX + wv * QX + i) * 64 + lane));
#pragma unroll
      for (int mi = 0; mi < 4; ++mi) {
        const v8bf a = xf[(size_t)(mi * KSX + wv * QX + i) * 64 + lane];
#pragma unroll
        for (int g = 0; g < 4; ++g)
          acc[mi][g] = __builtin_amdgcn_mfma_f32_16x16x32_bf16(a, bxl[g], acc[mi][g], 0, 0, 0);
      }
    }

    if (t > 0) {
      if (wv == 0) {   // group barrier: 64 lanes poll 4 padded sub-counters
        const unsigned need = 16u * (unsigned)t;
        unsigned* sc = &gflags[(lane & 3) * 64];
        while (true) {
          unsigned v = __hip_atomic_load(sc, __ATOMIC_RELAXED, __HIP_MEMORY_SCOPE_AGENT);
          if (__ballot(v >= need) == ~0ull) break;
          __builtin_amdgcn_s_sleep(4);
        }
      }
      __syncthreads();   // release all waves past the barrier

      if (p.rot) {
        // ---- phase H (cached multicast): step-t buffer address is FRESH
        // (129-slot rotation) => no stale-line hazard in any L1/L2 (gfx9 has
        // no HW L2 prefetch; dispatch acquire invalidates across launches).
        // Plain cached loads let the 8 same-group blocks of an XCD share ONE
        // LLC fetch through their XCD L2 (was: 64 unicast sc0|sc1 LLC reads,
        // 32 MB/step at ~3.2 TB/s = the old 10.4 us/step floor). Loads go
        // straight to VGPRs: no LDS round-trip, no r7 vmcnt hazard.
        const v8bf* hf = (const v8bf*)(p.hbuf + (size_t)t * (size_t)(kB * kH));
#pragma unroll
        for (int mi = 0; mi < 4; ++mi) {
          v8bf av[QH];   // bounded in-flight window: +32 VGPRs peak
#pragma unroll
          for (int i = 0; i < QH; ++i)
            av[i] = hf[(size_t)((mt * 4 + mi) * KSH + wv * QH + i) * 64 + lane];
#pragma unroll
          for (int i = 0; i < QH; ++i)
#pragma unroll
            for (int g = 0; g < 4; ++g)
              acc[mi][g] = __builtin_amdgcn_mfma_f32_16x16x32_bf16(av[i], bhh[i][g],
                                                                   acc[mi][g], 0, 0, 0);
        }
      } else {
        // ---- phase H (fallback, 2-slot): stage 32 KB h chunk via coherent
        // global_load_lds (LLC-serviced), then ds_read + MFMA.
        const char* hread = (const char*)(p.hbuf + (size_t)(t & 1) * kB * kH);
        char* myHs = smem + wv * 32768;
#pragma unroll
        for (int mi = 0; mi < 4; ++mi)
#pragma unroll
          for (int i = 0; i < QH; ++i) {
            const size_t sl = (size_t)((mt * 4 + mi) * KSH + wv * QH + i);
            ld16c(hread + sl * 1024 + lane * 16, myHs + (mi * QH + i) * 1024);
          }

        // r7 BUG FIX: global_load_lds results are NOT visible to ds_read until
        // vmcnt drains; the compiler does not track this dependency.
        __syncthreads();

#pragma unroll
        for (int mi = 0; mi < 4; ++mi)
#pragma unroll
          for (int i = 0; i < QH; ++i) {
            const v8bf a = *(const v8bf*)(myHs + (mi * QH + i) * 1024 + lane * 16);
#pragma unroll
            for (int g = 0; g < 4; ++g)
              acc[mi][g] = __builtin_amdgcn_mfma_f32_16x16x32_bf16(a, bhh[i][g],
                                                                   acc[mi][g], 0, 0, 0);
          }
      }
    }

    __syncthreads();   // phase-H done in all waves: Red overlay now safe

    // ---- cross-wave K-reduction through LDS ----
#pragma unroll
    for (int m = 0; m < 4; ++m)
#pragma unroll
      for (int g = 0; g < 4; ++g)
        Red[(wv * 16 + g * 4 + m) * 64 + lane] = acc[m][g];
    __syncthreads();

    // combine: this thread owns rows mt*64+wv*16+q*4+{0..3}, unit uglob
    v4f gacc[4];
#pragma unroll
    for (int g = 0; g < 4; ++g) {
      v4f s = Red[(0 * 16 + g * 4 + wv) * 64 + lane];
#pragma unroll
      for (int wvp = 1; wvp < 4; ++wvp) {
        const v4f z = Red[(wvp * 16 + g * 4 + wv) * 64 + lane];
#pragma unroll
        for (int r = 0; r < 4; ++r) s[r] += z[r];
      }
      gacc[g] = s;
    }

    // gates -> h; repack through Hout so global stores are coalesced 8B
#pragma unroll
    for (int r = 0; r < 4; ++r) {
      const float iv = sigm(gacc[0][r] + bias[0]);
      const float fv = sigm(gacc[1][r] + bias[1]);
      const float gv = tanh_f(gacc[2][r] + bias[2]);
      const float ov = sigm(gacc[3][r] + bias[3]);
      creg[r] = fv * creg[r] + iv * gv;
      const float hv = ov * tanh_f(creg[r]);
      Hout[(wv * 16 + q * 4 + r) * 16 + mloc] = f2b(hv);
    }
    __syncthreads();   // Hout complete

    // coalesced write-through: frag layout [slice][L][j]; this block's h =
    // 8 contiguous 256B runs: (mi 0..3) x (hbit 0..1) at slice byte off hi*256.
    // Stores stay sc0|sc1 (write-through to LLC) so the first consumer L2
    // miss in the rotation path is guaranteed to fetch the fresh line.
    {
      u16* hw = p.hbuf + (size_t)(p.rot ? (t + 1) : ((t + 1) & 1)) * (size_t)(kB * kH);
      const int c = tid >> 5;          // chunk 0..7
      const int mi_s = c >> 1;
      const int hbit = c & 1;
      const int hi = (ut * 2 + hbit) & 3;
      const int row16 = (tid & 31) >> 1;
      const int j0 = (tid & 1) * 4;
      const u64 v = *(const u64*)&Hout[(mi_s * 16 + row16) * 16 + hbit * 8 + j0];
      u64* dst = (u64*)((char*)hw + ((size_t)((mt * 4 + mi_s) * KSH + (ut >> 1)) * 1024)
                        + hi * 256 + row16 * 16 + j0 * 2);
      __hip_atomic_store(dst, v, __ATOMIC_RELAXED, __HIP_MEMORY_SCOPE_AGENT);
    }

    __syncthreads();   // drains vmcnt: all h stores acked at LLC (r4-validated)
    if (tid == 0)
      __hip_atomic_fetch_add(&gflags[(ut & 3) * 64], 1u, __ATOMIC_RELAXED,
                             __HIP_MEMORY_SCOPE_AGENT);
  }

  // ---- FC + log_softmax: blocks 0..31, 8 rows x 32 cols ----
  if (blk < 32) {
    const int gg = blk >> 3;   // mt of rows blk*8..+8
    if (wv == 0) {
      const unsigned need = 16u * (unsigned)kT;
      unsigned* sc = &p.flags[gg * 256 + (lane & 3) * 64];
      while (true) {
        unsigned v = __hip_atomic_load(sc, __ATOMIC_RELAXED, __HIP_MEMORY_SCOPE_AGENT);
        if (__ballot(v >= need) == ~0ull) break;
        __builtin_amdgcn_s_sleep(4);
      }
    }
    __syncthreads();
    // stage 8 rows from frag-layout h_last into shFC[row][u] (small, once)
    {
      const int mi = (blk >> 1) & 3;
      const int ks2 = tid >> 3;        // 0..31
      const int ug = (tid >> 1) & 3;   // unit 8-group
      const int rh = tid & 1;          // row half
      u64* hf = (u64*)(p.hbuf + (size_t)(p.rot ? kT : 0) * (size_t)(kB * kH));
#pragma unroll
      for (int rr = 0; rr < 4; ++rr) {
        const int row_l = rh * 4 + rr;
        const int r16 = (blk & 1) * 8 + row_l;
        const int L = r16 | (ug << 4);
        const size_t fi = ((size_t)((gg * 4 + mi) * KSH + ks2) * 64 + L) * 2;
        const u64 a = __hip_atomic_load(hf + fi, __ATOMIC_RELAXED, __HIP_MEMORY_SCOPE_AGENT);
        const u64 b = __hip_atomic_load(hf + fi + 1, __ATOMIC_RELAXED, __HIP_MEMORY_SCOPE_AGENT);
        u64* d = (u64*)&shFC[row_l * kH + ks2 * 32 + ug * 8];
        d[0] = a; d[1] = b;
      }
    }
    __syncthreads();
    const int row = tid >> 5;
    const int col = tid & 31;
    const u16* hr = &shFC[row * kH];
    const float* wr = p.wfc + (size_t)col * kH;
    float s = 0.f;
    for (int k = 0; k < kH; k += 4) {
      const float4 w4 = *(const float4*)(wr + k);
      s += b2f(hr[k]) * w4.x + b2f(hr[k + 1]) * w4.y +
           b2f(hr[k + 2]) * w4.z + b2f(hr[k + 3]) * w4.w;
    }
    float mx = s;
#pragma unroll
    for (int off = 16; off; off >>= 1) mx = fmaxf(mx, __shfl_xor(mx, off, 32));
    const float ex = __expf(s - mx);
    float se = ex;
#pragma unroll
    for (int off = 16; off; off >>= 1) se += __shfl_xor(se, off, 32);
    p.out[(blk * 8 + row) * kO + col] = s - mx - __logf(se);
  }
}

extern "C" void kernel_launch(void* const* d_in, const int* in_sizes, int n_in,
                              void* d_out, int out_size, void* d_ws, size_t ws_size,
                              hipStream_t stream) {
  (void)in_sizes; (void)n_in; (void)out_size;
  char* ws = (char*)d_ws;

  u16* xt = (u16*)(ws + OFF_XT);
  u16 *wit[4], *wht[4];
  for (int g = 0; g < 4; ++g) {
    wit[g] = (u16*)(ws + OFF_WIT + (size_t)g * SZ_WIT);
    wht[g] = (u16*)(ws + OFF_WHT + (size_t)g * SZ_WHT);
  }

  // dict order: x, (w_ii,w_hi,b_ii,b_hi), (w_if,w_hf,b_if,b_hf),
  //             (w_io,w_ho,b_io,b_ho), (w_ic,w_hc,b_ic,b_hc), w_fc
  // gate order: 0=i, 1=f, 2=g(candidate), 3=o
  const int gsrc[4] = {1, 5, 13, 9};

  hipMemsetAsync(d_ws, 0, 8192, stream);   // zero barrier flags

  cvt_x_tile<<<8192, 256, 0, stream>>>((const float*)d_in[0], xt);
  for (int g = 0; g < 4; ++g) {
    cvt_w_tile<<<256, 256, 0, stream>>>((const float*)d_in[gsrc[g]], wit[g], kI, 4);
    cvt_w_tile<<<512, 256, 0, stream>>>((const float*)d_in[gsrc[g] + 1], wht[g], kH, 5);
  }

  LstmParams p;
  p.xt = xt;
  for (int g = 0; g < 4; ++g) {
    p.wit[g] = wit[g];
    p.wht[g] = wht[g];
    p.bi[g] = (const float*)d_in[gsrc[g] + 2];
    p.bh[g] = (const float*)d_in[gsrc[g] + 3];
  }
  p.wfc = (const float*)d_in[17];
  p.out = (float*)d_out;
  p.flags = (unsigned*)(ws + OFF_FLG);
  p.hbuf = (u16*)(ws + OFF_H);
  // 129-slot rotation needs ~109 MB; fall back to the proven 2-slot coherent
  // path (baseline behavior) if the harness workspace is smaller.
  p.rot = (ws_size >= NEED_ROT) ? 1 : 0;

  void* args[] = {&p};
  hipError_t e = hipLaunchCooperativeKernel((void*)lstm_kernel, dim3(kBlocks),
                                            dim3(kThreads), args, 0, stream);
  if (e != hipSuccess) {
    // Never fail silently (r5 lesson). At this resource envelope >=1 block/CU
    // fits, so a 256-block plain launch co-schedules all blocks safely.
    (void)hipGetLastError();   // clear sticky error
    lstm_kernel<<<dim3(kBlocks), dim3(kThreads), 0, stream>>>(p);
  }
}

// Round 2
// 2449.439 us; speedup vs baseline: 1.0125x; 1.0125x over previous
//
#include <hip/hip_runtime.h>
#include <stdint.h>

#define GAS __attribute__((address_space(1)))
#define LAS __attribute__((address_space(3)))

typedef __bf16 v8bf __attribute__((ext_vector_type(8)));
typedef float v4f __attribute__((ext_vector_type(4)));
typedef unsigned short u16;
typedef unsigned long long u64;

constexpr int kB = 256, kT = 128, kI = 512, kH = 1024, kO = 32;
constexpr int kBlocks = 256, kThreads = 256;
constexpr int KSX = kI / 32;   // 16 k-slices of 32 in x
constexpr int KSH = kH / 32;   // 32 k-slices of 32 in h
constexpr int QX = KSX / 4;    // 4  x-slices per wave (k-split)
constexpr int QH = KSH / 4;    // 8  h-slices per wave

// workspace layout (bytes): FLG | XT | WIT[4] | WHT[4] | H slots (tail,
// variable count S = min(129, fit(ws_size)); S=2 degenerates to the proven
// r0 parity double-buffer).
constexpr size_t OFF_FLG  = 0;
constexpr size_t OFF_XT   = 8192;
constexpr size_t SZ_XT    = (size_t)kB * kT * kI * 2;           // 32 MB
constexpr size_t OFF_WIT  = OFF_XT + SZ_XT;
constexpr size_t SZ_WIT   = (size_t)kH * kI * 2;                // 1 MB / gate
constexpr size_t OFF_WHT  = OFF_WIT + 4 * SZ_WIT;
constexpr size_t SZ_WHT   = (size_t)kH * kH * 2;                // 2 MB / gate
constexpr size_t OFF_H    = OFF_WHT + 4 * SZ_WHT;               // ~44.2 MB
constexpr size_t SZ_H1    = (size_t)kB * kH * 2;                // 512 KB / slot

struct LstmParams {
  const u16* xt;        // frag-tiled x: [t][mt][mi][ks(16)][lane][8]
  const u16* wit[4];    // frag-tiled wi: [ut][ks(16)][lane][8], gates i,f,g,o
  const u16* wht[4];    // frag-tiled wh: [ut][ks(32)][lane][8]
  const float* bi[4];
  const float* bh[4];
  const float* wfc;     // fp32 [O][H]
  float* out;           // fp32 [B][O]
  unsigned* flags;      // [4 groups][64 producers], 16B stride (PRIVATE lines:
                        // r8 lesson — shared release counters starve under
                        // poll traffic and cost +7.3 us/step)
  u16* hbuf;            // S x frag-layout h slots: [mt][mi][ks(32)][lane][8]
  int slots;            // S: h[t] lives in slot t for t<S (FRESH address ->
                        // plain cached reads, L2-multicast); t>=S recycles
                        // slots {0,1} with sc0|sc1 coherent reads (L2-bypass,
                        // so stale cached lines from the slots' earlier life
                        // are harmless). S=2 == r0 parity scheme exactly.
};

static __device__ __forceinline__ float b2f(u16 v) {
  union { float f; uint32_t i; } u; u.i = ((uint32_t)v) << 16; return u.f;
}
static __device__ __forceinline__ u16 f2b(float f) {
  union { float f; uint32_t i; } u; u.f = f;
  return (u16)((u.i + 0x7fffu + ((u.i >> 16) & 1u)) >> 16);
}
static __device__ __forceinline__ float sigm(float x) { return 1.f / (1.f + __expf(-x)); }
static __device__ __forceinline__ float tanh_f(float x) {
  float e = __expf(2.f * x);
  return 1.f - 2.f / (e + 1.f);
}
// coherent async global->LDS, 16B/lane, sc0|sc1 (bypass L1/L2, LLC-serviced).
// Recycled-slot path only (r2-r4 proven). RULE (r7): a vmcnt(0) wait must sit
// between the issue and any ds_read of the destination.
static __device__ __forceinline__ void ld16c(const void* g, void* l) {
  __builtin_amdgcn_global_load_lds((const GAS uint32_t*)g, (LAS uint32_t*)l, 16, 0, 0x11);
}

// ---- prepass: fp32 -> bf16 frag-tiling -------------------------------------
// x[m][t][k] -> xt frag order [t][mt][mi][ks][lane][8]
__global__ __launch_bounds__(256) void cvt_x_tile(const float* __restrict__ x,
                                                  u16* __restrict__ xt) {
  const int gid = blockIdx.x * 256 + threadIdx.x;    // 2^21 threads exactly
  const int lane = gid & 63;
  const int ks = (gid >> 6) & 15;
  const int mi = (gid >> 10) & 3;
  const int mt = (gid >> 12) & 3;
  const int t  = gid >> 14;
  const int m = mt * 64 + mi * 16 + (lane & 15);
  const int k = ks * 32 + (lane >> 4) * 8;
  const float4* s = (const float4*)(x + ((size_t)m * kT + t) * kI + k);
  const float4 a = s[0], b = s[1];
  uint4 o = {f2b(a.x) | ((uint32_t)f2b(a.y) << 16), f2b(a.z) | ((uint32_t)f2b(a.w) << 16),
             f2b(b.x) | ((uint32_t)f2b(b.y) << 16), f2b(b.z) | ((uint32_t)f2b(b.w) << 16)};
  *(uint4*)(xt + (size_t)gid * 8) = o;
}

// W[u][k] (row-major, K=512 or 1024) -> frag order [ut][ks][lane][8]
__global__ __launch_bounds__(256) void cvt_w_tile(const float* __restrict__ w,
                                                  u16* __restrict__ wt,
                                                  int K, int lgKS) {
  const int gid = blockIdx.x * 256 + threadIdx.x;
  const int lane = gid & 63;
  const int rest = gid >> 6;
  const int ks = rest & ((1 << lgKS) - 1);
  const int ut2 = rest >> lgKS;
  const int u = ut2 * 16 + (lane & 15);
  const int k = ks * 32 + (lane >> 4) * 8;
  const float4* s = (const float4*)(w + (size_t)u * K + k);
  const float4 a = s[0], b = s[1];
  uint4 o = {f2b(a.x) | ((uint32_t)f2b(a.y) << 16), f2b(a.z) | ((uint32_t)f2b(a.w) << 16),
             f2b(b.x) | ((uint32_t)f2b(b.y) << 16), f2b(b.z) | ((uint32_t)f2b(b.w) << 16)};
  *(uint4*)(wt + (size_t)gid * 8) = o;
}

// ---- persistent recurrence kernel ------------------------------------------
__global__ __launch_bounds__(kThreads, 2) void lstm_kernel(LstmParams p) {
  // LDS map: [0,128K) per-wave h staging chunks (recycled-slot path only);
  // Red (64 KB) overlaid on [0,64K). [128K,130K) Hout repack tile. shFC
  // (16 KB) overlaid at 0 post-loop.
  __shared__ __align__(16) char smem[133120];
  v4f* Red = (v4f*)smem;              // [slot = wvp*16+g*4+m][lane]
  u16* Hout = (u16*)(smem + 131072);  // [64 rows][16 units]
  u16* shFC = (u16*)smem;             // 8 rows x 1024 bf16 (post-loop only)

  const int tid = threadIdx.x;
  const int lane = tid & 63;
  const int wv = tid >> 6;           // wave = K-quarter owner AND m-tile owner in combine
  const int blk = blockIdx.x;
  const int mt = blk & 3;            // batch tile 0..3 = barrier group
  const int ut = blk >> 2;           // 0..63: 16 hidden units (x4 gates)

  const int mloc = lane & 15;
  const int q = lane >> 4;
  const int uglob = ut * 16 + mloc;

  unsigned* gflags = p.flags + mt * 256;   // 64 slots, stride 4 u32 (16B)

  float bias[4];
#pragma unroll
  for (int g = 0; g < 4; ++g) bias[g] = p.bi[g][uglob] + p.bh[g][uglob];

  float creg[4] = {0.f, 0.f, 0.f, 0.f};    // cell state for rows mt*64+wv*16+q*4+r

  // ---- h-weights resident in registers (128 VGPRs); x-weights streamed ----
  v8bf bhh[QH][4];
#pragma unroll
  for (int g = 0; g < 4; ++g)
#pragma unroll
    for (int i = 0; i < QH; ++i)
      bhh[i][g] = *((const v8bf*)p.wht[g] + ((size_t)(ut * KSH + wv * QH + i) * 64 + lane));

  for (int t = 0; t < kT; ++t) {
    v4f acc[4][4];    // [m-tile][gate] partials for this wave's K-quarter
#pragma unroll
    for (int m = 0; m < 4; ++m)
#pragma unroll
      for (int g = 0; g < 4; ++g) acc[m][g] = (v4f){0.f, 0.f, 0.f, 0.f};

    // ---- phase X: x-part MFMAs, pre-poll (independent of h); wi from L2 ----
    const v8bf* xf = (const v8bf*)p.xt + ((size_t)(t * 4 + mt) * 4 * KSX) * 64;
#pragma unroll
    for (int i = 0; i < QX; ++i) {
      v8bf bxl[4];
#pragma unroll
      for (int g = 0; g < 4; ++g)
        bxl[g] = *((const v8bf*)p.wit[g] + ((size_t)(ut * KSX + wv * QX + i) * 64 + lane));
#pragma unroll
      for (int mi = 0; mi < 4; ++mi) {
        const v8bf a = xf[(size_t)(mi * KSX + wv * QX + i) * 64 + lane];
#pragma unroll
        for (int g = 0; g < 4; ++g)
          acc[mi][g] = __builtin_amdgcn_mfma_f32_16x16x32_bf16(a, bxl[g], acc[mi][g], 0, 0, 0);
      }
    }

    if (t > 0) {
      if (wv == 0) {   // group barrier: 64 lanes poll 64 PRIVATE padded flags
        while (true) {
          unsigned v = __hip_atomic_load(&gflags[lane * 4], __ATOMIC_RELAXED,
                                         __HIP_MEMORY_SCOPE_AGENT);
          if (__ballot(v >= (unsigned)t) == ~0ull) break;
          __builtin_amdgcn_s_sleep(1);
        }
      }
      __syncthreads();   // release all waves past the barrier

      if (t < p.slots) {
        // ---- phase H (cached multicast): slot t is a FRESH address (never
        // read or cached by any L1/L2 in this dispatch; dispatch-start acquire
        // invalidates L2s across launches). Plain cached loads let same-group
        // blocks on an XCD share ONE LLC fetch through their XCD L2 (vs 64
        // unicast sc0|sc1 LLC reads = 32 MB/step = the 10.4 us/step floor).
        // Loads go straight to VGPRs: no LDS round-trip, no r7 vmcnt hazard.
        const v8bf* hf = (const v8bf*)(p.hbuf + (size_t)t * (size_t)(kB * kH));
#pragma unroll
        for (int mi = 0; mi < 4; ++mi) {
          v8bf av[QH];   // bounded in-flight window: +32 VGPRs peak
#pragma unroll
          for (int i = 0; i < QH; ++i)
            av[i] = hf[(size_t)((mt * 4 + mi) * KSH + wv * QH + i) * 64 + lane];
#pragma unroll
          for (int i = 0; i < QH; ++i)
#pragma unroll
            for (int g = 0; g < 4; ++g)
              acc[mi][g] = __builtin_amdgcn_mfma_f32_16x16x32_bf16(av[i], bhh[i][g],
                                                                   acc[mi][g], 0, 0, 0);
        }
      } else {
        // ---- phase H (recycled slots {0,1}): stage 32 KB h chunk via
        // coherent global_load_lds (L2-bypass, LLC-serviced -> stale cached
        // lines from the slot's earlier life are invisible), then ds_read.
        const char* hread = (const char*)(p.hbuf + (size_t)((t - p.slots) & 1) * kB * kH);
        char* myHs = smem + wv * 32768;
#pragma unroll
        for (int mi = 0; mi < 4; ++mi)
#pragma unroll
          for (int i = 0; i < QH; ++i) {
            const size_t sl = (size_t)((mt * 4 + mi) * KSH + wv * QH + i);
            ld16c(hread + sl * 1024 + lane * 16, myHs + (mi * QH + i) * 1024);
          }

        // r7 BUG FIX: global_load_lds results are NOT visible to ds_read until
        // vmcnt drains; the compiler does not track this dependency.
        __syncthreads();

#pragma unroll
        for (int mi = 0; mi < 4; ++mi)
#pragma unroll
          for (int i = 0; i < QH; ++i) {
            const v8bf a = *(const v8bf*)(myHs + (mi * QH + i) * 1024 + lane * 16);
#pragma unroll
            for (int g = 0; g < 4; ++g)
              acc[mi][g] = __builtin_amdgcn_mfma_f32_16x16x32_bf16(a, bhh[i][g],
                                                                   acc[mi][g], 0, 0, 0);
          }
      }
    }

    __syncthreads();   // phase-H done in all waves: Red overlay now safe

    // ---- cross-wave K-reduction through LDS ----
#pragma unroll
    for (int m = 0; m < 4; ++m)
#pragma unroll
      for (int g = 0; g < 4; ++g)
        Red[(wv * 16 + g * 4 + m) * 64 + lane] = acc[m][g];
    __syncthreads();

    // combine: this thread owns rows mt*64+wv*16+q*4+{0..3}, unit uglob
    v4f gacc[4];
#pragma unroll
    for (int g = 0; g < 4; ++g) {
      v4f s = Red[(0 * 16 + g * 4 + wv) * 64 + lane];
#pragma unroll
      for (int wvp = 1; wvp < 4; ++wvp) {
        const v4f z = Red[(wvp * 16 + g * 4 + wv) * 64 + lane];
#pragma unroll
        for (int r = 0; r < 4; ++r) s[r] += z[r];
      }
      gacc[g] = s;
    }

    // gates -> h; repack through Hout so global stores are coalesced 8B
#pragma unroll
    for (int r = 0; r < 4; ++r) {
      const float iv = sigm(gacc[0][r] + bias[0]);
      const float fv = sigm(gacc[1][r] + bias[1]);
      const float gv = tanh_f(gacc[2][r] + bias[2]);
      const float ov = sigm(gacc[3][r] + bias[3]);
      creg[r] = fv * creg[r] + iv * gv;
      const float hv = ov * tanh_f(creg[r]);
      Hout[(wv * 16 + q * 4 + r) * 16 + mloc] = f2b(hv);
    }
    __syncthreads();   // Hout complete

    // coalesced write-through: frag layout [slice][L][j]; this block's h =
    // 8 contiguous 256B runs: (mi 0..3) x (hbit 0..1) at slice byte off hi*256.
    // Stores stay sc0|sc1 (write-through to LLC) so the first consumer L2
    // miss in the fresh-slot path is guaranteed to fetch the fresh line.
    {
      const int ts = t + 1;
      const int wslot = (ts < p.slots) ? ts : ((ts - p.slots) & 1);
      u16* hw = p.hbuf + (size_t)wslot * (size_t)(kB * kH);
      const int c = tid >> 5;          // chunk 0..7
      const int mi_s = c >> 1;
      const int hbit = c & 1;
      const int hi = (ut * 2 + hbit) & 3;
      const int row16 = (tid & 31) >> 1;
      const int j0 = (tid & 1) * 4;
      const u64 v = *(const u64*)&Hout[(mi_s * 16 + row16) * 16 + hbit * 8 + j0];
      u64* dst = (u64*)((char*)hw + ((size_t)((mt * 4 + mi_s) * KSH + (ut >> 1)) * 1024)
                        + hi * 256 + row16 * 16 + j0 * 2);
      __hip_atomic_store(dst, v, __ATOMIC_RELAXED, __HIP_MEMORY_SCOPE_AGENT);
    }

    __syncthreads();   // drains vmcnt: all h stores acked at LLC (r4-validated)
    if (tid == 0)
      __hip_atomic_fetch_add(&gflags[ut * 4], 1u, __ATOMIC_RELAXED,
                             __HIP_MEMORY_SCOPE_AGENT);
  }

  // ---- FC + log_softmax: blocks 0..31, 8 rows x 32 cols ----
  if (blk < 32) {
    const int gg = blk >> 3;   // mt of rows blk*8..+8
    if (wv == 0) {
      while (true) {
        unsigned v = __hip_atomic_load(&p.flags[gg * 256 + lane * 4], __ATOMIC_RELAXED,
                                       __HIP_MEMORY_SCOPE_AGENT);
        if (__ballot(v >= (unsigned)kT) == ~0ull) break;
        __builtin_amdgcn_s_sleep(1);
      }
    }
    __syncthreads();
    // stage 8 rows from frag-layout h_last into shFC[row][u] (small, once)
    {
      const int mi = (blk >> 1) & 3;
      const int ks2 = tid >> 3;        // 0..31
      const int ug = (tid >> 1) & 3;   // unit 8-group
      const int rh = tid & 1;          // row half
      const int fslot = (kT < p.slots) ? kT : ((kT - p.slots) & 1);
      u64* hf = (u64*)(p.hbuf + (size_t)fslot * (size_t)(kB * kH));
#pragma unroll
      for (int rr = 0; rr < 4; ++rr) {
        const int row_l = rh * 4 + rr;
        const int r16 = (blk & 1) * 8 + row_l;
        const int L = r16 | (ug << 4);
        const size_t fi = ((size_t)((gg * 4 + mi) * KSH + ks2) * 64 + L) * 2;
        const u64 a = __hip_atomic_load(hf + fi, __ATOMIC_RELAXED, __HIP_MEMORY_SCOPE_AGENT);
        const u64 b = __hip_atomic_load(hf + fi + 1, __ATOMIC_RELAXED, __HIP_MEMORY_SCOPE_AGENT);
        u64* d = (u64*)&shFC[row_l * kH + ks2 * 32 + ug * 8];
        d[0] = a; d[1] = b;
      }
    }
    __syncthreads();
    const int row = tid >> 5;
    const int col = tid & 31;
    const u16* hr = &shFC[row * kH];
    const float* wr = p.wfc + (size_t)col * kH;
    float s = 0.f;
    for (int k = 0; k < kH; k += 4) {
      const float4 w4 = *(const float4*)(wr + k);
      s += b2f(hr[k]) * w4.x + b2f(hr[k + 1]) * w4.y +
           b2f(hr[k + 2]) * w4.z + b2f(hr[k + 3]) * w4.w;
    }
    float mx = s;
#pragma unroll
    for (int off = 16; off; off >>= 1) mx = fmaxf(mx, __shfl_xor(mx, off, 32));
    const float ex = __expf(s - mx);
    float se = ex;
#pragma unroll
    for (int off = 16; off; off >>= 1) se += __shfl_xor(se, off, 32);
    p.out[(blk * 8 + row) * kO + col] = s - mx - __logf(se);
  }
}

extern "C" void kernel_launch(void* const* d_in, const int* in_sizes, int n_in,
                              void* d_out, int out_size, void* d_ws, size_t ws_size,
                              hipStream_t stream) {
  (void)in_sizes; (void)n_in; (void)out_size;
  char* ws = (char*)d_ws;

  u16* xt = (u16*)(ws + OFF_XT);
  u16 *wit[4], *wht[4];
  for (int g = 0; g < 4; ++g) {
    wit[g] = (u16*)(ws + OFF_WIT + (size_t)g * SZ_WIT);
    wht[g] = (u16*)(ws + OFF_WHT + (size_t)g * SZ_WHT);
  }

  // dict order: x, (w_ii,w_hi,b_ii,b_hi), (w_if,w_hf,b_if,b_hf),
  //             (w_io,w_ho,b_io,b_ho), (w_ic,w_hc,b_ic,b_hc), w_fc
  // gate order: 0=i, 1=f, 2=g(candidate), 3=o
  const int gsrc[4] = {1, 5, 13, 9};

  hipMemsetAsync(d_ws, 0, 8192, stream);   // zero barrier flags

  cvt_x_tile<<<8192, 256, 0, stream>>>((const float*)d_in[0], xt);
  for (int g = 0; g < 4; ++g) {
    cvt_w_tile<<<256, 256, 0, stream>>>((const float*)d_in[gsrc[g]], wit[g], kI, 4);
    cvt_w_tile<<<512, 256, 0, stream>>>((const float*)d_in[gsrc[g] + 1], wht[g], kH, 5);
  }

  LstmParams p;
  p.xt = xt;
  for (int g = 0; g < 4; ++g) {
    p.wit[g] = wit[g];
    p.wht[g] = wht[g];
    p.bi[g] = (const float*)d_in[gsrc[g] + 2];
    p.bh[g] = (const float*)d_in[gsrc[g] + 3];
  }
  p.wfc = (const float*)d_in[17];
  p.out = (float*)d_out;
  p.flags = (unsigned*)(ws + OFF_FLG);
  p.hbuf = (u16*)(ws + OFF_H);
  // Adaptive slot count: as many fresh 512KB h slots as the workspace holds,
  // capped at kT+1 (fully fresh). S=2 reproduces r0's parity scheme exactly.
  {
    size_t avail = (ws_size > OFF_H) ? (ws_size - OFF_H) / SZ_H1 : 0;
    int S = (avail > (size_t)(kT + 1)) ? (kT + 1) : (int)avail;
    if (S < 2) S = 2;
    p.slots = S;
  }

  void* args[] = {&p};
  hipError_t e = hipLaunchCooperativeKernel((void*)lstm_kernel, dim3(kBlocks),
                                            dim3(kThreads), args, 0, stream);
  if (e != hipSuccess) {
    // Never fail silently (r5 lesson). At this resource envelope >=1 block/CU
    // fits, so a 256-block plain launch co-schedules all blocks safely.
    (void)hipGetLastError();   // clear sticky error
    lstm_kernel<<<dim3(kBlocks), dim3(kThreads), 0, stream>>>(p);
  }
}

// Round 3
// 1444.457 us; speedup vs baseline: 1.7169x; 1.6958x over previous
//
#include <hip/hip_runtime.h>
#include <stdint.h>

#define GAS __attribute__((address_space(1)))
#define LAS __attribute__((address_space(3)))

typedef __bf16 v8bf __attribute__((ext_vector_type(8)));
typedef float v4f __attribute__((ext_vector_type(4)));
typedef unsigned short u16;
typedef unsigned long long u64;

constexpr int kB = 256, kT = 128, kI = 512, kH = 1024, kO = 32;
constexpr int kBlocks = 256, kThreads = 256;
constexpr int KSX = kI / 32;   // 16 k-slices of 32 in x
constexpr int KSH = kH / 32;   // 32 k-slices of 32 in h
constexpr int QX = KSX / 4;    // 4  x-slices per wave (k-split)
constexpr int QH = KSH / 4;    // 8  h-slices per wave

// workspace layout (bytes) — EXACT r0 layout. ws_size is ~45 MB (r1/r2
// probes proved the 109 MB rotation never engaged), so the 2-slot parity
// double-buffer is the only viable h exchange.
constexpr size_t OFF_FLG = 0;                                   // flags[4][64], 16B stride
constexpr size_t OFF_H   = 8192;                                // 2 x 512KB frag-layout h
constexpr size_t SZ_H    = (size_t)2 * kB * kH * 2;
constexpr size_t OFF_XT  = OFF_H + SZ_H;                        // frag-tiled x (bf16)
constexpr size_t SZ_XT   = (size_t)kB * kT * kI * 2;            // 32 MB
constexpr size_t OFF_WIT = OFF_XT + SZ_XT;                      // 4 x 1MB wi frag tiles
constexpr size_t SZ_WIT  = (size_t)kH * kI * 2;
constexpr size_t OFF_WHT = OFF_WIT + 4 * SZ_WIT;                // 4 x 2MB wh frag tiles
constexpr size_t SZ_WHT  = (size_t)kH * kH * 2;

struct LstmParams {
  const u16* xt;        // frag-tiled x: [t][mt][mi][ks(16)][lane][8]
  const u16* wit[4];    // frag-tiled wi: [ut][ks(16)][lane][8], gates i,f,g,o
  const u16* wht[4];    // frag-tiled wh: [ut][ks(32)][lane][8]
  const float* bi[4];
  const float* bh[4];
  const float* wfc;     // fp32 [O][H]
  float* out;           // fp32 [B][O]
  unsigned* flags;      // [4][64], 16B stride (PRIVATE producer lines)
  u16* hbuf;            // 2 x frag-layout h: [mt][mi][ks(32)][lane][8]
};

static __device__ __forceinline__ float b2f(u16 v) {
  union { float f; uint32_t i; } u; u.i = ((uint32_t)v) << 16; return u.f;
}
static __device__ __forceinline__ u16 f2b(float f) {
  union { float f; uint32_t i; } u; u.f = f;
  return (u16)((u.i + 0x7fffu + ((u.i >> 16) & 1u)) >> 16);
}
static __device__ __forceinline__ float sigm(float x) { return 1.f / (1.f + __expf(-x)); }
static __device__ __forceinline__ float tanh_f(float x) {
  float e = __expf(2.f * x);
  return 1.f - 2.f / (e + 1.f);
}
// coherent async global->LDS, 16B/lane, sc0|sc1 (bypass L1/L2, LLC-serviced).
// r2-r4 PROVEN fast coherent-read path. RULE (r7): a vmcnt wait MUST sit
// between the issue and any ds_read of the destination — the compiler cannot
// see the LDS dependency through the AS(3) pointer. This round the wait is a
// COUNTED per-wave s_waitcnt (m135-verified semantics: waits until at most N
// vmem ops outstanding; loads complete oldest-first in program order), each
// followed by sched_barrier(0) per methodology rule #18.
static __device__ __forceinline__ void ld16c(const void* g, void* l) {
  __builtin_amdgcn_global_load_lds((const GAS uint32_t*)g, (LAS uint32_t*)l, 16, 0, 0x11);
}

// ---- prepass: fp32 -> bf16 frag-tiling -------------------------------------
// x[m][t][k] -> xt frag order [t][mt][mi][ks][lane][8]
__global__ __launch_bounds__(256) void cvt_x_tile(const float* __restrict__ x,
                                                  u16* __restrict__ xt) {
  const int gid = blockIdx.x * 256 + threadIdx.x;    // 2^21 threads exactly
  const int lane = gid & 63;
  const int ks = (gid >> 6) & 15;
  const int mi = (gid >> 10) & 3;
  const int mt = (gid >> 12) & 3;
  const int t  = gid >> 14;
  const int m = mt * 64 + mi * 16 + (lane & 15);
  const int k = ks * 32 + (lane >> 4) * 8;
  const float4* s = (const float4*)(x + ((size_t)m * kT + t) * kI + k);
  const float4 a = s[0], b = s[1];
  uint4 o = {f2b(a.x) | ((uint32_t)f2b(a.y) << 16), f2b(a.z) | ((uint32_t)f2b(a.w) << 16),
             f2b(b.x) | ((uint32_t)f2b(b.y) << 16), f2b(b.z) | ((uint32_t)f2b(b.w) << 16)};
  *(uint4*)(xt + (size_t)gid * 8) = o;
}

// W[u][k] (row-major, K=512 or 1024) -> frag order [ut][ks][lane][8]
__global__ __launch_bounds__(256) void cvt_w_tile(const float* __restrict__ w,
                                                  u16* __restrict__ wt,
                                                  int K, int lgKS) {
  const int gid = blockIdx.x * 256 + threadIdx.x;
  const int lane = gid & 63;
  const int rest = gid >> 6;
  const int ks = rest & ((1 << lgKS) - 1);
  const int ut2 = rest >> lgKS;
  const int u = ut2 * 16 + (lane & 15);
  const int k = ks * 32 + (lane >> 4) * 8;
  const float4* s = (const float4*)(w + (size_t)u * K + k);
  const float4 a = s[0], b = s[1];
  uint4 o = {f2b(a.x) | ((uint32_t)f2b(a.y) << 16), f2b(a.z) | ((uint32_t)f2b(a.w) << 16),
             f2b(b.x) | ((uint32_t)f2b(b.y) << 16), f2b(b.z) | ((uint32_t)f2b(b.w) << 16)};
  *(uint4*)(wt + (size_t)gid * 8) = o;
}

// ---- persistent recurrence kernel ------------------------------------------
__global__ __launch_bounds__(kThreads, 2) void lstm_kernel(LstmParams p) {
  // LDS map: [0,128K) per-wave h staging chunks (32 KB each); Red (64 KB)
  // overlaid on [0,64K) — protected by the barrier after phase-H consume.
  // [128K,130K) Hout repack tile. shFC (16 KB) overlaid at 0 post-loop.
  __shared__ __align__(16) char smem[133120];
  v4f* Red = (v4f*)smem;              // [slot = wvp*16+g*4+m][lane]
  u16* Hout = (u16*)(smem + 131072);  // [64 rows][16 units]
  u16* shFC = (u16*)smem;             // 8 rows x 1024 bf16 (post-loop only)

  const int tid = threadIdx.x;
  const int lane = tid & 63;
  const int wv = tid >> 6;           // wave = K-quarter owner AND m-tile owner in combine
  const int blk = blockIdx.x;
  const int mt = blk & 3;            // batch tile 0..3 = barrier group
  const int ut = blk >> 2;           // 0..63: 16 hidden units (x4 gates)

  const int mloc = lane & 15;
  const int q = lane >> 4;
  const int uglob = ut * 16 + mloc;

  unsigned* gflags = p.flags + mt * 256;   // 64 slots, stride 4 u32 (16B)

  float bias[4];
#pragma unroll
  for (int g = 0; g < 4; ++g) bias[g] = p.bi[g][uglob] + p.bh[g][uglob];

  float creg[4] = {0.f, 0.f, 0.f, 0.f};    // cell state for rows mt*64+wv*16+q*4+r

  // ---- h-weights resident in registers (128 VGPRs); x-weights streamed ----
  v8bf bhh[QH][4];
#pragma unroll
  for (int g = 0; g < 4; ++g)
#pragma unroll
    for (int i = 0; i < QH; ++i)
      bhh[i][g] = *((const v8bf*)p.wht[g] + ((size_t)(ut * KSH + wv * QH + i) * 64 + lane));

  for (int t = 0; t < kT; ++t) {
    v4f acc[4][4];    // [m-tile][gate] partials for this wave's K-quarter
#pragma unroll
    for (int m = 0; m < 4; ++m)
#pragma unroll
      for (int g = 0; g < 4; ++g) acc[m][g] = (v4f){0.f, 0.f, 0.f, 0.f};

    // ---- phase X: x-part MFMAs, pre-poll (independent of h); wi from L2 ----
    const v8bf* xf = (const v8bf*)p.xt + ((size_t)(t * 4 + mt) * 4 * KSX) * 64;
#pragma unroll
    for (int i = 0; i < QX; ++i) {
      v8bf bxl[4];
#pragma unroll
      for (int g = 0; g < 4; ++g)
        bxl[g] = *((const v8bf*)p.wit[g] + ((size_t)(ut * KSX + wv * QX + i) * 64 + lane));
#pragma unroll
      for (int mi = 0; mi < 4; ++mi) {
        const v8bf a = xf[(size_t)(mi * KSX + wv * QX + i) * 64 + lane];
#pragma unroll
        for (int g = 0; g < 4; ++g)
          acc[mi][g] = __builtin_amdgcn_mfma_f32_16x16x32_bf16(a, bxl[g], acc[mi][g], 0, 0, 0);
      }
    }

    if (t > 0) {
      if (wv == 0) {   // group barrier: 64 lanes poll 64 PRIVATE padded flags
        while (true) {
          unsigned v = __hip_atomic_load(&gflags[lane * 4], __ATOMIC_RELAXED,
                                         __HIP_MEMORY_SCOPE_AGENT);
          if (__ballot(v >= (unsigned)t) == ~0ull) break;
          __builtin_amdgcn_s_sleep(1);
        }
      }
      __syncthreads();   // release all waves past the barrier

      // ---- phase H: stage this wave's 32 KB h chunk via coherent
      //      global_load_lds (LLC-serviced). NEW vs r0: counted-vmcnt split —
      //      issue all 32 loads, drain to 16 (halves mi=0,1 landed), MFMA on
      //      them while halves mi=2,3 stream, then drain to 0. Also removes
      //      the block-wide r7 __syncthreads from the critical path (each
      //      wave reads only its own 32 KB region; vmcnt is per-wave).
      //      At phase-H entry vmcnt==0 (phase-X loads consumed by MFMAs; the
      //      previous step's h-stores drained at the end-of-step barrier), so
      //      the outstanding-op count here is exactly the 32 ld16c issues.
      const char* hread = (const char*)(p.hbuf + (size_t)(t & 1) * kB * kH);
      char* myHs = smem + wv * 32768;
#pragma unroll
      for (int mi = 0; mi < 4; ++mi)
#pragma unroll
        for (int i = 0; i < QH; ++i) {
          const size_t sl = (size_t)((mt * 4 + mi) * KSH + wv * QH + i);
          ld16c(hread + sl * 1024 + lane * 16, myHs + (mi * QH + i) * 1024);
        }

      // halves mi=0,1 (oldest 16 issues) complete when <=16 remain outstanding
      asm volatile("s_waitcnt vmcnt(16)" ::: "memory");
      __builtin_amdgcn_sched_barrier(0);
#pragma unroll
      for (int mi = 0; mi < 2; ++mi)
#pragma unroll
        for (int i = 0; i < QH; ++i) {
          const v8bf a = *(const v8bf*)(myHs + (mi * QH + i) * 1024 + lane * 16);
#pragma unroll
          for (int g = 0; g < 4; ++g)
            acc[mi][g] = __builtin_amdgcn_mfma_f32_16x16x32_bf16(a, bhh[i][g], acc[mi][g], 0, 0, 0);
        }

      asm volatile("s_waitcnt vmcnt(0)" ::: "memory");
      __builtin_amdgcn_sched_barrier(0);
#pragma unroll
      for (int mi = 2; mi < 4; ++mi)
#pragma unroll
        for (int i = 0; i < QH; ++i) {
          const v8bf a = *(const v8bf*)(myHs + (mi * QH + i) * 1024 + lane * 16);
#pragma unroll
          for (int g = 0; g < 4; ++g)
            acc[mi][g] = __builtin_amdgcn_mfma_f32_16x16x32_bf16(a, bhh[i][g], acc[mi][g], 0, 0, 0);
        }
    }

    __syncthreads();   // all phase-H ds_reads done: Red overlay now safe

    // ---- cross-wave K-reduction through LDS ----
#pragma unroll
    for (int m = 0; m < 4; ++m)
#pragma unroll
      for (int g = 0; g < 4; ++g)
        Red[(wv * 16 + g * 4 + m) * 64 + lane] = acc[m][g];
    __syncthreads();

    // combine: this thread owns rows mt*64+wv*16+q*4+{0..3}, unit uglob
    v4f gacc[4];
#pragma unroll
    for (int g = 0; g < 4; ++g) {
      v4f s = Red[(0 * 16 + g * 4 + wv) * 64 + lane];
#pragma unroll
      for (int wvp = 1; wvp < 4; ++wvp) {
        const v4f z = Red[(wvp * 16 + g * 4 + wv) * 64 + lane];
#pragma unroll
        for (int r = 0; r < 4; ++r) s[r] += z[r];
      }
      gacc[g] = s;
    }

    // gates -> h; repack through Hout so global stores are coalesced 8B
#pragma unroll
    for (int r = 0; r < 4; ++r) {
      const float iv = sigm(gacc[0][r] + bias[0]);
      const float fv = sigm(gacc[1][r] + bias[1]);
      const float gv = tanh_f(gacc[2][r] + bias[2]);
      const float ov = sigm(gacc[3][r] + bias[3]);
      creg[r] = fv * creg[r] + iv * gv;
      const float hv = ov * tanh_f(creg[r]);
      Hout[(wv * 16 + q * 4 + r) * 16 + mloc] = f2b(hv);
    }
    __syncthreads();   // Hout complete

    // coalesced write-through: frag layout [slice][L][j]; this block's h =
    // 8 contiguous 256B runs: (mi 0..3) x (hbit 0..1) at slice byte off hi*256
    {
      u16* hw = p.hbuf + (size_t)((t + 1) & 1) * kB * kH;
      const int c = tid >> 5;          // chunk 0..7
      const int mi_s = c >> 1;
      const int hbit = c & 1;
      const int hi = (ut * 2 + hbit) & 3;
      const int row16 = (tid & 31) >> 1;
      const int j0 = (tid & 1) * 4;
      const u64 v = *(const u64*)&Hout[(mi_s * 16 + row16) * 16 + hbit * 8 + j0];
      u64* dst = (u64*)((char*)hw + ((size_t)((mt * 4 + mi_s) * KSH + (ut >> 1)) * 1024)
                        + hi * 256 + row16 * 16 + j0 * 2);
      __hip_atomic_store(dst, v, __ATOMIC_RELAXED, __HIP_MEMORY_SCOPE_AGENT);
    }

    __syncthreads();   // drains vmcnt: all h stores acked at LLC (r4-validated)
    if (tid == 0)
      __hip_atomic_fetch_add(&gflags[ut * 4], 1u, __ATOMIC_RELAXED,
                             __HIP_MEMORY_SCOPE_AGENT);
  }

  // ---- FC + log_softmax: blocks 0..31, 8 rows x 32 cols. h_last in buf 0 ----
  if (blk < 32) {
    const int gg = blk >> 3;   // mt of rows blk*8..+8
    if (wv == 0) {
      while (true) {
        unsigned v = __hip_atomic_load(&p.flags[gg * 256 + lane * 4], __ATOMIC_RELAXED,
                                       __HIP_MEMORY_SCOPE_AGENT);
        if (__ballot(v >= (unsigned)kT) == ~0ull) break;
        __builtin_amdgcn_s_sleep(1);
      }
    }
    __syncthreads();
    // stage 8 rows from frag-layout h into shFC[row][u] (small, once)
    {
      const int mi = (blk >> 1) & 3;
      const int ks2 = tid >> 3;        // 0..31
      const int ug = (tid >> 1) & 3;   // unit 8-group
      const int rh = tid & 1;          // row half
      u64* hf = (u64*)p.hbuf;          // buffer 0 (kT even)
#pragma unroll
      for (int rr = 0; rr < 4; ++rr) {
        const int row_l = rh * 4 + rr;
        const int r16 = (blk & 1) * 8 + row_l;
        const int L = r16 | (ug << 4);
        const size_t fi = ((size_t)((gg * 4 + mi) * KSH + ks2) * 64 + L) * 2;
        const u64 a = __hip_atomic_load(hf + fi, __ATOMIC_RELAXED, __HIP_MEMORY_SCOPE_AGENT);
        const u64 b = __hip_atomic_load(hf + fi + 1, __ATOMIC_RELAXED, __HIP_MEMORY_SCOPE_AGENT);
        u64* d = (u64*)&shFC[row_l * kH + ks2 * 32 + ug * 8];
        d[0] = a; d[1] = b;
      }
    }
    __syncthreads();
    const int row = tid >> 5;
    const int col = tid & 31;
    const u16* hr = &shFC[row * kH];
    const float* wr = p.wfc + (size_t)col * kH;
    float s = 0.f;
    for (int k = 0; k < kH; k += 4) {
      const float4 w4 = *(const float4*)(wr + k);
      s += b2f(hr[k]) * w4.x + b2f(hr[k + 1]) * w4.y +
           b2f(hr[k + 2]) * w4.z + b2f(hr[k + 3]) * w4.w;
    }
    float mx = s;
#pragma unroll
    for (int off = 16; off; off >>= 1) mx = fmaxf(mx, __shfl_xor(mx, off, 32));
    const float ex = __expf(s - mx);
    float se = ex;
#pragma unroll
    for (int off = 16; off; off >>= 1) se += __shfl_xor(se, off, 32);
    p.out[(blk * 8 + row) * kO + col] = s - mx - __logf(se);
  }
}

extern "C" void kernel_launch(void* const* d_in, const int* in_sizes, int n_in,
                              void* d_out, int out_size, void* d_ws, size_t ws_size,
                              hipStream_t stream) {
  (void)in_sizes; (void)n_in; (void)out_size; (void)ws_size;
  char* ws = (char*)d_ws;

  u16* xt = (u16*)(ws + OFF_XT);
  u16 *wit[4], *wht[4];
  for (int g = 0; g < 4; ++g) {
    wit[g] = (u16*)(ws + OFF_WIT + (size_t)g * SZ_WIT);
    wht[g] = (u16*)(ws + OFF_WHT + (size_t)g * SZ_WHT);
  }

  // dict order: x, (w_ii,w_hi,b_ii,b_hi), (w_if,w_hf,b_if,b_hf),
  //             (w_io,w_ho,b_io,b_ho), (w_ic,w_hc,b_ic,b_hc), w_fc
  // gate order: 0=i, 1=f, 2=g(candidate), 3=o
  const int gsrc[4] = {1, 5, 13, 9};

  hipMemsetAsync(d_ws, 0, 8192, stream);   // zero barrier flags

  cvt_x_tile<<<8192, 256, 0, stream>>>((const float*)d_in[0], xt);
  for (int g = 0; g < 4; ++g) {
    cvt_w_tile<<<256, 256, 0, stream>>>((const float*)d_in[gsrc[g]], wit[g], kI, 4);
    cvt_w_tile<<<512, 256, 0, stream>>>((const float*)d_in[gsrc[g] + 1], wht[g], kH, 5);
  }

  LstmParams p;
  p.xt = xt;
  for (int g = 0; g < 4; ++g) {
    p.wit[g] = wit[g];
    p.wht[g] = wht[g];
    p.bi[g] = (const float*)d_in[gsrc[g] + 2];
    p.bh[g] = (const float*)d_in[gsrc[g] + 3];
  }
  p.wfc = (const float*)d_in[17];
  p.out = (float*)d_out;
  p.flags = (unsigned*)(ws + OFF_FLG);
  p.hbuf = (u16*)(ws + OFF_H);

  void* args[] = {&p};
  hipError_t e = hipLaunchCooperativeKernel((void*)lstm_kernel, dim3(kBlocks),
                                            dim3(kThreads), args, 0, stream);
  if (e != hipSuccess) {
    // Never fail silently (r5 lesson). At this resource envelope >=1 block/CU
    // fits, so a 256-block plain launch co-schedules all blocks safely.
    (void)hipGetLastError();   // clear sticky error
    lstm_kernel<<<dim3(kBlocks), dim3(kThreads), 0, stream>>>(p);
  }
}